// Round 11
// baseline (586.204 us; speedup 1.0000x reference)
//
#include <hip/hip_runtime.h>
#include <hip/hip_bf16.h>
#include <math.h>

#define HC 768   // 3F concat width (bf16 elements)
#define DPB 8    // dsts owned per block in edge kernel

typedef __attribute__((ext_vector_type(8))) short bf16x8;  // 8 bf16 (4 VGPRs)
typedef __attribute__((ext_vector_type(4))) float f32x4;   // MFMA accumulator

__device__ __forceinline__ float bf2f(unsigned short h) {
    return __uint_as_float(((unsigned)h) << 16);
}
__device__ __forceinline__ unsigned short f2bf(float f) {   // round-to-nearest-even
    unsigned u = __float_as_uint(f);
    return (unsigned short)((u + 0x7fffu + ((u >> 16) & 1u)) >> 16);
}
// packed 2xf32 -> 2xbf16 (v_cvt_pk_bf16_f32 on gfx950)
__device__ __forceinline__ unsigned pack_bf2(float a, float b) {
    __hip_bfloat162 h = __float22bfloat162_rn(make_float2(a, b));
    return *reinterpret_cast<unsigned*>(&h);
}

// order-preserving float->uint encoding for max
__device__ __forceinline__ unsigned enc_f(float f) {
    unsigned u = __float_as_uint(f);
    return (u & 0x80000000u) ? ~u : (u | 0x80000000u);
}
__device__ __forceinline__ float dec_f(unsigned e) {
    unsigned u = (e & 0x80000000u) ? (e & 0x7FFFFFFFu) : ~e;
    return __uint_as_float(u);
}
#define ENC_NEG_INF 0x007FFFFFu  // enc(-inf)

// ---- fused: precompute (blocks [0,nPre)) + weight prep (blocks [nPre,..)) ---
__global__ void pre_and_prep_kernel(const float* __restrict__ x,
                                    const float* __restrict__ t,
                                    const float* __restrict__ emb,
                                    const float* __restrict__ enc_W,
                                    const float* __restrict__ enc_b,
                                    const float* __restrict__ fw,
                                    const float* __restrict__ te_W,
                                    const float* __restrict__ te_b,
                                    unsigned short* __restrict__ hcat,
                                    float* __restrict__ invstd,
                                    const float* __restrict__ W1a,
                                    const float* __restrict__ W1b,
                                    const float* __restrict__ W1c,
                                    const float* __restrict__ W2a,
                                    const float* __restrict__ W2b,
                                    const float* __restrict__ W2c,
                                    unsigned short* __restrict__ WcatT,
                                    unsigned short* __restrict__ W2T,
                                    unsigned short* __restrict__ W2T3,
                                    int N, int nPre) {
    __shared__ float smem[64 * 65];   // union: ti[8][256]+tv[8] | buf[64][65]
    const int tid = threadIdx.x;

    if ((int)blockIdx.x < nPre) {
        float (*ti)[256] = (float(*)[256])smem;
        float* tv = smem + 8 * 256;
        const int n0 = blockIdx.x * 8;

        if (tid < 8) {
            int n = n0 + tid;
            float tt = (n < N) ? t[n] : 1.0f;
            tv[tid] = tt;
            const float ln_s = 3.2188758248682006f; // ln(25)
            float p = expf(2.0f * tt * ln_s);       // SIGMA^(2t)
            float sd = sqrtf((p - 1.0f) / (2.0f * ln_s));
            if (n < N) invstd[n] = 1.0f / (sd + 1e-7f);
        }
        __syncthreads();

        const float TWO_PI = 6.283185307179586f;
        for (int p = tid; p < 8 * 128; p += 256) {
            int n = p >> 7, j = p & 127;
            float pr = tv[n] * fw[j] * TWO_PI;
            ti[n][j]       = sinf(pr);
            ti[n][j + 128] = cosf(pr);
        }
        __syncthreads();

        const int j = tid;
        float acc[8];
#pragma unroll
        for (int n = 0; n < 8; ++n) acc[n] = 0.f;
        for (int k = 0; k < 256; ++k) {
            float w = te_W[k * 256 + j];
#pragma unroll
            for (int n = 0; n < 8; ++n) acc[n] += ti[n][k] * w;
        }
        float bj  = te_b[j];
        float ew0 = enc_W[0 * 256 + j], ew1 = enc_W[1 * 256 + j], ew2 = enc_W[2 * 256 + j];
        float ebj = enc_b[j];
        for (int n = 0; n < 8; ++n) {
            int node = n0 + n;
            if (node >= N) break;
            float v = acc[n] + bj;
            float temb = v / (1.0f + expf(-v));   // silu
            float h0 = x[node * 3 + 0] * ew0 + x[node * 3 + 1] * ew1 +
                       x[node * 3 + 2] * ew2 + ebj;
            hcat[(size_t)node * HC + j]       = f2bf(h0);
            hcat[(size_t)node * HC + 256 + j] = f2bf(temb);
            hcat[(size_t)node * HC + 512 + j] = f2bf(emb[node * 256 + j]);
        }
    } else {
        float (*buf)[65] = (float(*)[65])smem;
        const int bid = blockIdx.x - nPre;
        const int tx = tid & 63, ty = tid >> 6;

        if (bid < 288) {
            const int l = bid / 96, r = bid - l * 96;
            const float* W1 = (l == 0) ? W1a : (l == 1) ? W1b : W1c;
            unsigned short* WT = WcatT + (size_t)l * 512 * 768;
            const int k0 = (r % 12) * 64, n0 = (r / 12) * 64;
#pragma unroll
            for (int i = 0; i < 16; ++i) {
                int kl = ty + i * 4;
                int k = k0 + kl, n = n0 + tx;
                float v = (n < 256) ? (W1[(size_t)k * 256 + n] - W1[(size_t)(k + 768) * 256 + n])
                                    : W1[(size_t)(k + 768) * 256 + (n - 256)];
                buf[kl][tx] = v;
            }
            __syncthreads();
#pragma unroll
            for (int i = 0; i < 16; ++i) {
                int nl = ty + i * 4;
                WT[(size_t)(n0 + nl) * 768 + k0 + tx] = f2bf(buf[tx][nl]);
            }
        } else if (bid < 320) {
            const int m = bid - 288, l = m >> 4, r = m & 15;
            const float* W2 = (l == 0) ? W2a : W2b;
            unsigned short* WT = W2T + (size_t)l * 256 * 256;
            const int k0 = (r & 3) * 64, n0 = (r >> 2) * 64;
#pragma unroll
            for (int i = 0; i < 16; ++i) {
                int kl = ty + i * 4;
                buf[kl][tx] = W2[(size_t)(k0 + kl) * 256 + n0 + tx];
            }
            __syncthreads();
#pragma unroll
            for (int i = 0; i < 16; ++i) {
                int nl = ty + i * 4;
                WT[(size_t)(n0 + nl) * 256 + k0 + tx] = f2bf(buf[tx][nl]);
            }
        } else {
            int idx = (bid - 320) * 256 + tid;   // 16*256
            int n = idx >> 8, k = idx & 255;
            W2T3[idx] = (n < 3) ? f2bf(W2c[(size_t)k * 3 + n]) : (unsigned short)0;
        }
    }
}

// ------- RQ (N x 512 bf16) = hcat (N x 768 bf16) @ WcatT^T; R += b1 ---------
// wave tile 32 rows x 64 cols, acc[2][4]; block = 64 rows x 128 cols.
__global__ __launch_bounds__(256)
void node_gemm_mfma_kernel(const unsigned short* __restrict__ A,
                           const unsigned short* __restrict__ BT,  // [512][768]
                           const float* __restrict__ b1,
                           unsigned short* __restrict__ C,
                           int M) {
    const int row0 = blockIdx.x * 64, col0 = blockIdx.y * 128;
    const int tid = threadIdx.x;
    const int wv = tid >> 6, lane = tid & 63;
    const int q = lane >> 4, nl = lane & 15;
    const int rbase = row0 + (wv >> 1) * 32;
    const int cbase = col0 + (wv & 1) * 64;

    int r0c = min(rbase + nl, M - 1);
    int r1c = min(rbase + 16 + nl, M - 1);
    const unsigned short* pa0 = A + (size_t)r0c * HC + q * 8;
    const unsigned short* pa1 = A + (size_t)r1c * HC + q * 8;

    f32x4 acc[2][4];
#pragma unroll
    for (int s = 0; s < 2; ++s)
#pragma unroll
        for (int t = 0; t < 4; ++t) acc[s][t] = (f32x4){0.f, 0.f, 0.f, 0.f};

    for (int ks = 0; ks < 24; ++ks) {
        const int k0 = ks * 32;
        const bf16x8 av0 = *(const bf16x8*)(pa0 + k0);
        const bf16x8 av1 = *(const bf16x8*)(pa1 + k0);
#pragma unroll
        for (int t = 0; t < 4; ++t) {
            const bf16x8 bv = *(const bf16x8*)(BT + (size_t)(cbase + t * 16 + nl) * 768 + k0 + q * 8);
            acc[0][t] = __builtin_amdgcn_mfma_f32_16x16x32_bf16(av0, bv, acc[0][t], 0, 0, 0);
            acc[1][t] = __builtin_amdgcn_mfma_f32_16x16x32_bf16(av1, bv, acc[1][t], 0, 0, 0);
        }
    }

#pragma unroll
    for (int s = 0; s < 2; ++s) {
        const int rr = rbase + s * 16 + q * 4;
#pragma unroll
        for (int t = 0; t < 4; ++t) {
            int col = cbase + t * 16 + nl;
            float bb = (col < 256) ? b1[col] : 0.f;
#pragma unroll
            for (int i = 0; i < 4; ++i) {
                int r = rr + i;
                if (r < M) C[(size_t)r * 512 + col] = f2bf(acc[s][t][i] + bb);
            }
        }
    }
}

// ---------------- edge sort by dst + init ------------------------------------
__global__ void init_kernel(unsigned* __restrict__ cnt, unsigned* __restrict__ seg3, int N) {
    int idx = blockIdx.x * 256 + threadIdx.x;
    if (idx < 2 * N) cnt[idx] = 0u;
    else if (idx < 5 * N) seg3[idx - 2 * N] = ENC_NEG_INF;
}
__global__ void hist_kernel(const int* __restrict__ dst, unsigned* __restrict__ cnt, int E) {
    int e = blockIdx.x * 256 + threadIdx.x;
    if (e < E) atomicAdd(&cnt[dst[e]], 1u);
}
// shuffle-based scan: wave shfl_up scan + 16-wave LDS combine (4 barriers/chunk)
__global__ void scan_kernel(const unsigned* __restrict__ cnt,
                            int* __restrict__ row_start, int N) {
    __shared__ unsigned wexc[16];
    __shared__ unsigned chunk_total;
    __shared__ unsigned carry;
    const int tid = threadIdx.x, wv = tid >> 6, ln = tid & 63;
    if (tid == 0) carry = 0u;
    __syncthreads();
    for (int base = 0; base < N; base += 1024) {
        int i = base + tid;
        unsigned v = (i < N) ? cnt[i] : 0u;
        unsigned s = v;
#pragma unroll
        for (int off = 1; off < 64; off <<= 1) {
            unsigned o = __shfl_up(s, off);
            if (ln >= off) s += o;
        }
        if (ln == 63) wexc[wv] = s;       // wave totals
        __syncthreads();
        if (tid < 16) {
            unsigned ws = wexc[tid];
            unsigned tt = ws;
#pragma unroll
            for (int off = 1; off < 16; off <<= 1) {
                unsigned o = __shfl_up(tt, off);
                if (tid >= off) tt += o;
            }
            wexc[tid] = tt - ws;          // exclusive wave offset
            if (tid == 15) chunk_total = tt;
        }
        __syncthreads();
        if (i < N) row_start[i] = (int)(carry + wexc[wv] + s - v);  // exclusive
        __syncthreads();
        if (tid == 0) carry += chunk_total;
        __syncthreads();
    }
    if (tid == 0) row_start[N] = (int)carry;  // == E
}
__global__ void scatter_kernel(const int* __restrict__ src, const int* __restrict__ dst,
                               const int* __restrict__ row_start,
                               unsigned* __restrict__ wcnt,
                               int* __restrict__ es, int* __restrict__ ed, int E) {
    int e = blockIdx.x * 256 + threadIdx.x;
    if (e >= E) return;
    int d = dst[e];
    int pos = row_start[d] + (int)atomicAdd(&wcnt[d], 1u);
    es[pos] = src[e];
    ed[pos] = d;
}

// ---- edges (layers 1,2): software-pipelined MFMA + dst-owner seg-max --------
// 32-edge halves, double-buffered af[2]. Each thread prefetches its next
// half's src gather into registers (svr) right after the barrier, BEFORE the
// current half's MFMAs -- the waitcnt lands in next iteration's combine, so
// gather latency hides behind the matrix pipe. No ss/sdl LDS (per-thread
// scalar es/ed reads, L2-hot).
__global__ __launch_bounds__(256, 3)
void edge_seg_gemm_kernel(const unsigned short* __restrict__ RQb,
                          const int* __restrict__ es,
                          const int* __restrict__ ed,
                          const int* __restrict__ row_start,   // N+1
                          const unsigned short* __restrict__ W2T,  // [256][256]
                          const float* __restrict__ b2,
                          unsigned short* __restrict__ hcat,
                          int N, int E) {
    __shared__ unsigned short af[2][32][264];    // 33.8 KB double buffer
    __shared__ unsigned short rdst[DPB][256];    // block's dst R-halves, 4 KB
    __shared__ unsigned lseg[DPB * 256];         // 8 KB
    const int d0 = blockIdx.x * DPB;
    const int tid = threadIdx.x;
    const int wv = tid >> 6, lane = tid & 63;
    const int q = lane >> 4, nl = lane & 15;

    for (int i = tid; i < DPB * 256; i += 256) lseg[i] = ENC_NEG_INF;

    // load 8 dst rows (R half: RQb[d][0..255]) into LDS, b128 per thread
    {
        int rrow = tid >> 5;            // 0..7
        int kc = (tid & 31) * 8;        // 0..248
        int d = d0 + rrow;
        int dc = (d < N) ? d : (N - 1);
        *(bf16x8*)&rdst[rrow][kc] = *(const bf16x8*)(RQb + (size_t)dc * 512 + kc);
    }

    const int eBeg = row_start[d0];
    const int eEnd = row_start[min(d0 + DPB, N)];
    const int H = (eEnd - eBeg + 31) >> 5;       // 32-edge halves

    // staging slot: this thread owns edge el of each half, k = kb + j*64
    const int el = tid >> 3;          // 0..31
    const int kb = (tid & 7) * 8;     // bank-spread map (r8, conflict-floor)

    __syncthreads();                  // rdst + lseg ready

    // prefetch half 0
    uint4 svr[4];
    int sdl_c = -1;
    {
        int e = eBeg + el;
        int ec = min(e, eEnd - 1); if (ec < 0) ec = 0;
        int srow = es[ec];
        sdl_c = (e < eEnd) ? (ed[ec] - d0) : -1;
        const unsigned short* ps = RQb + (size_t)srow * 512 + 256;
#pragma unroll
        for (int j = 0; j < 4; ++j) svr[j] = *(const uint4*)(ps + kb + j * 64);
    }

    for (int h = 0; h < H; ++h) {
        const int b = h & 1;
        const int c0 = eBeg + h * 32;

        // combine prefetched data -> af[b] (waits the svr loads here)
        {
            int dla = (sdl_c >= 0) ? sdl_c : 0;
#pragma unroll
            for (int j = 0; j < 4; ++j) {
                const int k = kb + j * 64;
                bf16x8 dv = *(const bf16x8*)&rdst[dla][k];
                bf16x8 sv = *(bf16x8*)&svr[j];
                float f[8];
#pragma unroll
                for (int u = 0; u < 8; ++u)
                    f[u] = fmaxf(bf2f((unsigned short)dv[u]) + bf2f((unsigned short)sv[u]), 0.f);
                uint4 o;
                o.x = pack_bf2(f[0], f[1]);
                o.y = pack_bf2(f[2], f[3]);
                o.z = pack_bf2(f[4], f[5]);
                o.w = pack_bf2(f[6], f[7]);
                *(uint4*)&af[b][el][k] = o;
            }
        }
        __syncthreads();   // af[b] ready; all mfma reads of af[b] (iter h-2) done

        // prefetch half h+1 (loads in flight across the MFMAs below)
        if (h + 1 < H) {
            int e = c0 + 32 + el;
            int ec = min(e, eEnd - 1);
            int srow = es[ec];
            sdl_c = (e < eEnd) ? (ed[ec] - d0) : -1;
            const unsigned short* ps = RQb + (size_t)srow * 512 + 256;
#pragma unroll
            for (int j = 0; j < 4; ++j) svr[j] = *(const uint4*)(ps + kb + j * 64);
        }

        // GEMM: 2 subtiles x 8 ks x 4 t, bv shared across subtiles
        f32x4 acc[2][4];
#pragma unroll
        for (int s = 0; s < 2; ++s)
#pragma unroll
            for (int t = 0; t < 4; ++t) acc[s][t] = (f32x4){0.f, 0.f, 0.f, 0.f};
#pragma unroll
        for (int ks = 0; ks < 8; ++ks) {
            const bf16x8 a0 = *(const bf16x8*)&af[b][nl][ks * 32 + q * 8];
            const bf16x8 a1 = *(const bf16x8*)&af[b][16 + nl][ks * 32 + q * 8];
#pragma unroll
            for (int t = 0; t < 4; ++t) {
                const bf16x8 bv = *(const bf16x8*)(W2T +
                    (size_t)(wv * 64 + t * 16 + nl) * 256 + ks * 32 + q * 8);
                acc[0][t] = __builtin_amdgcn_mfma_f32_16x16x32_bf16(a0, bv, acc[0][t], 0, 0, 0);
                acc[1][t] = __builtin_amdgcn_mfma_f32_16x16x32_bf16(a1, bv, acc[1][t], 0, 0, 0);
            }
        }

        // epilogue: lane holds rows m = sub*16 + q*4 + i, col = wv*64+t*16+nl
#pragma unroll
        for (int sub = 0; sub < 2; ++sub) {
            const int m0 = sub * 16 + q * 4;
            int dls[4];
#pragma unroll
            for (int i = 0; i < 4; ++i) {
                int e = c0 + m0 + i;
                dls[i] = (e < eEnd) ? (ed[e] - d0) : -1;
            }
#pragma unroll
            for (int t = 0; t < 4; ++t) {
                const int col = wv * 64 + t * 16 + nl;
                float cur = -INFINITY;
                int cd = dls[0];
#pragma unroll
                for (int i = 0; i < 4; ++i) {
                    int dl = dls[i];
                    if (dl != cd) {
                        if (cd >= 0) atomicMax(&lseg[cd * 256 + col], enc_f(cur));
                        cur = -INFINITY; cd = dl;
                    }
                    cur = fmaxf(cur, acc[sub][t][i]);
                }
                if (cd >= 0) atomicMax(&lseg[cd * 256 + col], enc_f(cur));
            }
        }
    }
    __syncthreads();

    // write relu(max + b2) (0 for empty segments) straight into hcat (bf16)
    for (int i = tid; i < DPB * 256; i += 256) {
        int dl = i >> 8, col = i & 255;
        int d = d0 + dl;
        if (d >= N) continue;
        float f = dec_f(lseg[i]);
        float v = isfinite(f) ? fmaxf(f + b2[col], 0.f) : 0.f;
        hcat[(size_t)d * HC + col] = f2bf(v);
    }
}

// ---- layer 3 edges via MFMA: one wave per 16 sorted edges -------------------
__global__ __launch_bounds__(256)
void edge3_mfma_kernel(const unsigned short* __restrict__ RQb,
                       const int* __restrict__ es,
                       const int* __restrict__ ed,
                       const unsigned short* __restrict__ W2T3,  // [16][256]
                       const float* __restrict__ b2,             // 3
                       unsigned* __restrict__ seg3,
                       int E) {
    const int wave = blockIdx.x * 4 + (threadIdx.x >> 6);
    const int lane = threadIdx.x & 63;
    const int q = lane >> 4, nl = lane & 15;
    const int e0 = wave * 16;
    if (e0 >= E) return;

    // hoist all 8 B fragments (col nl, k = ks*32 + q*8 ..+7)
    bf16x8 bv[8];
#pragma unroll
    for (int ks = 0; ks < 8; ++ks)
        bv[ks] = *(const bf16x8*)(W2T3 + (size_t)nl * 256 + ks * 32 + q * 8);

    // this lane's A row: edge e0 + nl
    int eA = e0 + nl;
    int eAc = (eA < E) ? eA : (E - 1);
    const int dA = ed[eAc], sA = es[eAc];
    const unsigned short* pd = RQb + (size_t)dA * 512 + q * 8;
    const unsigned short* ps = RQb + (size_t)sA * 512 + 256 + q * 8;

    f32x4 acc = (f32x4){0.f, 0.f, 0.f, 0.f};
#pragma unroll
    for (int ks = 0; ks < 8; ++ks) {
        bf16x8 dv = *(const bf16x8*)(pd + ks * 32);
        bf16x8 sv = *(const bf16x8*)(ps + ks * 32);
        float f[8];
#pragma unroll
        for (int u = 0; u < 8; ++u)
            f[u] = fmaxf(bf2f((unsigned short)dv[u]) + bf2f((unsigned short)sv[u]), 0.f);
        uint4 o;
        o.x = pack_bf2(f[0], f[1]);
        o.y = pack_bf2(f[2], f[3]);
        o.z = pack_bf2(f[4], f[5]);
        o.w = pack_bf2(f[6], f[7]);
        bf16x8 av = *(bf16x8*)&o;
        acc = __builtin_amdgcn_mfma_f32_16x16x32_bf16(av, bv[ks], acc, 0, 0, 0);
    }

    // epilogue: col = nl (only nl<3), rows = q*4+i -> edges e0+q*4+i
    if (nl < 3) {
        float bb = b2[nl];
        float cur = -INFINITY;
        int cd = -2;
#pragma unroll
        for (int i = 0; i < 4; ++i) {
            int e = e0 + q * 4 + i;
            int d = (e < E) ? ed[e] : -1;
            if (d != cd) {
                if (cd >= 0) atomicMax(&seg3[(size_t)cd * 3 + nl], enc_f(cur + bb));
                cur = -INFINITY; cd = d;
            }
            if (d >= 0) cur = fmaxf(cur, acc[i]);
        }
        if (cd >= 0) atomicMax(&seg3[(size_t)cd * 3 + nl], enc_f(cur + bb));
    }
}

// ---------------- misc ------------------------------------------------------
__global__ void finalize3_kernel(const unsigned* __restrict__ seg3,
                                 const float* __restrict__ invstd,
                                 float* __restrict__ out, int N) {
    int idx = blockIdx.x * 256 + threadIdx.x;
    if (idx >= N * 3) return;
    int n = idx / 3;
    float f = dec_f(seg3[idx]);
    if (!isfinite(f)) f = 0.f;
    out[idx] = f * invstd[n];
}

extern "C" void kernel_launch(void* const* d_in, const int* in_sizes, int n_in,
                              void* d_out, int out_size, void* d_ws, size_t ws_size,
                              hipStream_t stream) {
    const float* x     = (const float*)d_in[0];
    const int*   ei    = (const int*)d_in[1];
    const float* t     = (const float*)d_in[2];
    const float* emb   = (const float*)d_in[3];
    const float* enc_W = (const float*)d_in[4];
    const float* enc_b = (const float*)d_in[5];
    const float* fw    = (const float*)d_in[6];
    const float* te_W  = (const float*)d_in[7];
    const float* te_b  = (const float*)d_in[8];
    const float* W1[3] = {(const float*)d_in[9],  (const float*)d_in[13], (const float*)d_in[17]};
    const float* b1[3] = {(const float*)d_in[10], (const float*)d_in[14], (const float*)d_in[18]};
    const float* W2[3] = {(const float*)d_in[11], (const float*)d_in[15], (const float*)d_in[19]};
    const float* b2[3] = {(const float*)d_in[12], (const float*)d_in[16], (const float*)d_in[20]};

    const int N = in_sizes[2];      // t is (N,1)
    const int E = in_sizes[1] / 2;  // edge_index is (2,E)
    const int* src = ei;
    const int* dst = ei + E;

    char* ws = (char*)d_ws;
    unsigned short* hcat  = (unsigned short*)ws; ws += (size_t)N * HC * 2;          // bf16
    unsigned short* RQb   = (unsigned short*)ws; ws += (size_t)N * 512 * 2;         // bf16
    unsigned short* WcatT = (unsigned short*)ws; ws += (size_t)3 * 512 * 768 * 2;   // bf16 x3
    unsigned short* W2T   = (unsigned short*)ws; ws += (size_t)2 * 256 * 256 * 2;   // bf16 x2
    unsigned short* W2T3  = (unsigned short*)ws; ws += (size_t)16 * 256 * 2;        // bf16
    unsigned* seg3        = (unsigned*)ws;       ws += (size_t)N * 3 * 4;
    float*    invstd      = (float*)ws;          ws += (size_t)N * 4;
    int*      es          = (int*)ws;            ws += (size_t)E * 4;
    int*      ed          = (int*)ws;            ws += (size_t)E * 4;
    unsigned* cnt         = (unsigned*)ws;       ws += (size_t)N * 4;   // cnt+wcnt adjacent
    unsigned* wcnt        = (unsigned*)ws;       ws += (size_t)N * 4;
    int*      row_start   = (int*)ws;            ws += (size_t)(N + 1) * 4;

    // ---- init (cnt/wcnt zero + seg3 neg-inf) + counting sort ----
    init_kernel<<<(5 * N + 255) / 256, 256, 0, stream>>>(cnt, seg3, N);
    hist_kernel<<<(E + 255) / 256, 256, 0, stream>>>(dst, cnt, E);
    scan_kernel<<<1, 1024, 0, stream>>>(cnt, row_start, N);
    scatter_kernel<<<(E + 255) / 256, 256, 0, stream>>>(src, dst, row_start, wcnt, es, ed, E);

    // fused precompute + weight prep
    const int nPre = (N + 7) / 8;
    pre_and_prep_kernel<<<nPre + 336, 256, 0, stream>>>(
        x, t, emb, enc_W, enc_b, fw, te_W, te_b, hcat, invstd,
        W1[0], W1[1], W1[2], W2[0], W2[1], W2[2], WcatT, W2T, W2T3, N, nPre);

    for (int l = 0; l < 3; ++l) {
        dim3 gn((N + 63) / 64, 4);
        node_gemm_mfma_kernel<<<gn, 256, 0, stream>>>(
            hcat, WcatT + (size_t)l * 512 * 768, b1[l], RQb, N);
        if (l < 2) {
            edge_seg_gemm_kernel<<<(N + DPB - 1) / DPB, 256, 0, stream>>>(
                RQb, es, ed, row_start, W2T + (size_t)l * 256 * 256, b2[l], hcat, N, E);
        } else {
            int chunks = (E + 15) / 16;
            edge3_mfma_kernel<<<(chunks + 3) / 4, 256, 0, stream>>>(
                RQb, es, ed, W2T3, b2[l], seg3, E);
            finalize3_kernel<<<(N * 3 + 255) / 256, 256, 0, stream>>>(seg3, invstd, (float*)d_out, N);
        }
    }
}

// Round 12
// 485.496 us; speedup vs baseline: 1.2074x; 1.2074x over previous
//
#include <hip/hip_runtime.h>
#include <hip/hip_bf16.h>
#include <math.h>

#define HC 768   // 3F concat width (bf16 elements)
#define DPB 8    // dsts owned per block in edge kernel

typedef __attribute__((ext_vector_type(8))) short bf16x8;  // 8 bf16 (4 VGPRs)
typedef __attribute__((ext_vector_type(4))) float f32x4;   // MFMA accumulator

__device__ __forceinline__ float bf2f(unsigned short h) {
    return __uint_as_float(((unsigned)h) << 16);
}
__device__ __forceinline__ unsigned short f2bf(float f) {   // round-to-nearest-even
    unsigned u = __float_as_uint(f);
    return (unsigned short)((u + 0x7fffu + ((u >> 16) & 1u)) >> 16);
}
// packed 2xf32 -> 2xbf16 (v_cvt_pk_bf16_f32 on gfx950)
__device__ __forceinline__ unsigned pack_bf2(float a, float b) {
    __hip_bfloat162 h = __float22bfloat162_rn(make_float2(a, b));
    return *reinterpret_cast<unsigned*>(&h);
}

// order-preserving float->uint encoding for max
__device__ __forceinline__ unsigned enc_f(float f) {
    unsigned u = __float_as_uint(f);
    return (u & 0x80000000u) ? ~u : (u | 0x80000000u);
}
__device__ __forceinline__ float dec_f(unsigned e) {
    unsigned u = (e & 0x80000000u) ? (e & 0x7FFFFFFFu) : ~e;
    return __uint_as_float(u);
}
#define ENC_NEG_INF 0x007FFFFFu  // enc(-inf)

// ---- fused: precompute (blocks [0,nPre)) + weight prep (blocks [nPre,..)) ---
__global__ void pre_and_prep_kernel(const float* __restrict__ x,
                                    const float* __restrict__ t,
                                    const float* __restrict__ emb,
                                    const float* __restrict__ enc_W,
                                    const float* __restrict__ enc_b,
                                    const float* __restrict__ fw,
                                    const float* __restrict__ te_W,
                                    const float* __restrict__ te_b,
                                    unsigned short* __restrict__ hcat,
                                    float* __restrict__ invstd,
                                    const float* __restrict__ W1a,
                                    const float* __restrict__ W1b,
                                    const float* __restrict__ W1c,
                                    const float* __restrict__ W2a,
                                    const float* __restrict__ W2b,
                                    const float* __restrict__ W2c,
                                    unsigned short* __restrict__ WcatT,
                                    unsigned short* __restrict__ W2T,
                                    unsigned short* __restrict__ W2T3,
                                    int N, int nPre) {
    __shared__ float smem[64 * 65];   // union: ti[8][256]+tv[8] | buf[64][65]
    const int tid = threadIdx.x;

    if ((int)blockIdx.x < nPre) {
        float (*ti)[256] = (float(*)[256])smem;
        float* tv = smem + 8 * 256;
        const int n0 = blockIdx.x * 8;

        if (tid < 8) {
            int n = n0 + tid;
            float tt = (n < N) ? t[n] : 1.0f;
            tv[tid] = tt;
            const float ln_s = 3.2188758248682006f; // ln(25)
            float p = expf(2.0f * tt * ln_s);       // SIGMA^(2t)
            float sd = sqrtf((p - 1.0f) / (2.0f * ln_s));
            if (n < N) invstd[n] = 1.0f / (sd + 1e-7f);
        }
        __syncthreads();

        const float TWO_PI = 6.283185307179586f;
        for (int p = tid; p < 8 * 128; p += 256) {
            int n = p >> 7, j = p & 127;
            float pr = tv[n] * fw[j] * TWO_PI;
            ti[n][j]       = sinf(pr);
            ti[n][j + 128] = cosf(pr);
        }
        __syncthreads();

        const int j = tid;
        float acc[8];
#pragma unroll
        for (int n = 0; n < 8; ++n) acc[n] = 0.f;
        for (int k = 0; k < 256; ++k) {
            float w = te_W[k * 256 + j];
#pragma unroll
            for (int n = 0; n < 8; ++n) acc[n] += ti[n][k] * w;
        }
        float bj  = te_b[j];
        float ew0 = enc_W[0 * 256 + j], ew1 = enc_W[1 * 256 + j], ew2 = enc_W[2 * 256 + j];
        float ebj = enc_b[j];
        for (int n = 0; n < 8; ++n) {
            int node = n0 + n;
            if (node >= N) break;
            float v = acc[n] + bj;
            float temb = v / (1.0f + expf(-v));   // silu
            float h0 = x[node * 3 + 0] * ew0 + x[node * 3 + 1] * ew1 +
                       x[node * 3 + 2] * ew2 + ebj;
            hcat[(size_t)node * HC + j]       = f2bf(h0);
            hcat[(size_t)node * HC + 256 + j] = f2bf(temb);
            hcat[(size_t)node * HC + 512 + j] = f2bf(emb[node * 256 + j]);
        }
    } else {
        float (*buf)[65] = (float(*)[65])smem;
        const int bid = blockIdx.x - nPre;
        const int tx = tid & 63, ty = tid >> 6;

        if (bid < 288) {
            const int l = bid / 96, r = bid - l * 96;
            const float* W1 = (l == 0) ? W1a : (l == 1) ? W1b : W1c;
            unsigned short* WT = WcatT + (size_t)l * 512 * 768;
            const int k0 = (r % 12) * 64, n0 = (r / 12) * 64;
#pragma unroll
            for (int i = 0; i < 16; ++i) {
                int kl = ty + i * 4;
                int k = k0 + kl, n = n0 + tx;
                float v = (n < 256) ? (W1[(size_t)k * 256 + n] - W1[(size_t)(k + 768) * 256 + n])
                                    : W1[(size_t)(k + 768) * 256 + (n - 256)];
                buf[kl][tx] = v;
            }
            __syncthreads();
#pragma unroll
            for (int i = 0; i < 16; ++i) {
                int nl = ty + i * 4;
                WT[(size_t)(n0 + nl) * 768 + k0 + tx] = f2bf(buf[tx][nl]);
            }
        } else if (bid < 320) {
            const int m = bid - 288, l = m >> 4, r = m & 15;
            const float* W2 = (l == 0) ? W2a : W2b;
            unsigned short* WT = W2T + (size_t)l * 256 * 256;
            const int k0 = (r & 3) * 64, n0 = (r >> 2) * 64;
#pragma unroll
            for (int i = 0; i < 16; ++i) {
                int kl = ty + i * 4;
                buf[kl][tx] = W2[(size_t)(k0 + kl) * 256 + n0 + tx];
            }
            __syncthreads();
#pragma unroll
            for (int i = 0; i < 16; ++i) {
                int nl = ty + i * 4;
                WT[(size_t)(n0 + nl) * 256 + k0 + tx] = f2bf(buf[tx][nl]);
            }
        } else {
            int idx = (bid - 320) * 256 + tid;   // 16*256
            int n = idx >> 8, k = idx & 255;
            W2T3[idx] = (n < 3) ? f2bf(W2c[(size_t)k * 3 + n]) : (unsigned short)0;
        }
    }
}

// ------- RQ (N x 512 bf16) = hcat (N x 768 bf16) @ WcatT^T; R += b1 ---------
// wave tile 32 rows x 64 cols, acc[2][4]; block = 64 rows x 128 cols.
__global__ __launch_bounds__(256)
void node_gemm_mfma_kernel(const unsigned short* __restrict__ A,
                           const unsigned short* __restrict__ BT,  // [512][768]
                           const float* __restrict__ b1,
                           unsigned short* __restrict__ C,
                           int M) {
    const int row0 = blockIdx.x * 64, col0 = blockIdx.y * 128;
    const int tid = threadIdx.x;
    const int wv = tid >> 6, lane = tid & 63;
    const int q = lane >> 4, nl = lane & 15;
    const int rbase = row0 + (wv >> 1) * 32;
    const int cbase = col0 + (wv & 1) * 64;

    int r0c = min(rbase + nl, M - 1);
    int r1c = min(rbase + 16 + nl, M - 1);
    const unsigned short* pa0 = A + (size_t)r0c * HC + q * 8;
    const unsigned short* pa1 = A + (size_t)r1c * HC + q * 8;

    f32x4 acc[2][4];
#pragma unroll
    for (int s = 0; s < 2; ++s)
#pragma unroll
        for (int t = 0; t < 4; ++t) acc[s][t] = (f32x4){0.f, 0.f, 0.f, 0.f};

    for (int ks = 0; ks < 24; ++ks) {
        const int k0 = ks * 32;
        const bf16x8 av0 = *(const bf16x8*)(pa0 + k0);
        const bf16x8 av1 = *(const bf16x8*)(pa1 + k0);
#pragma unroll
        for (int t = 0; t < 4; ++t) {
            const bf16x8 bv = *(const bf16x8*)(BT + (size_t)(cbase + t * 16 + nl) * 768 + k0 + q * 8);
            acc[0][t] = __builtin_amdgcn_mfma_f32_16x16x32_bf16(av0, bv, acc[0][t], 0, 0, 0);
            acc[1][t] = __builtin_amdgcn_mfma_f32_16x16x32_bf16(av1, bv, acc[1][t], 0, 0, 0);
        }
    }

#pragma unroll
    for (int s = 0; s < 2; ++s) {
        const int rr = rbase + s * 16 + q * 4;
#pragma unroll
        for (int t = 0; t < 4; ++t) {
            int col = cbase + t * 16 + nl;
            float bb = (col < 256) ? b1[col] : 0.f;
#pragma unroll
            for (int i = 0; i < 4; ++i) {
                int r = rr + i;
                if (r < M) C[(size_t)r * 512 + col] = f2bf(acc[s][t][i] + bb);
            }
        }
    }
}

// ---------------- edge sort by dst + init ------------------------------------
__global__ void init_kernel(unsigned* __restrict__ cnt, unsigned* __restrict__ seg3, int N) {
    int idx = blockIdx.x * 256 + threadIdx.x;
    if (idx < 2 * N) cnt[idx] = 0u;
    else if (idx < 5 * N) seg3[idx - 2 * N] = ENC_NEG_INF;
}
__global__ void hist_kernel(const int* __restrict__ dst, unsigned* __restrict__ cnt, int E) {
    int e = blockIdx.x * 256 + threadIdx.x;
    if (e < E) atomicAdd(&cnt[dst[e]], 1u);
}
// shuffle-based scan: wave shfl_up scan + 16-wave LDS combine
__global__ void scan_kernel(const unsigned* __restrict__ cnt,
                            int* __restrict__ row_start, int N) {
    __shared__ unsigned wexc[16];
    __shared__ unsigned chunk_total;
    __shared__ unsigned carry;
    const int tid = threadIdx.x, wv = tid >> 6, ln = tid & 63;
    if (tid == 0) carry = 0u;
    __syncthreads();
    for (int base = 0; base < N; base += 1024) {
        int i = base + tid;
        unsigned v = (i < N) ? cnt[i] : 0u;
        unsigned s = v;
#pragma unroll
        for (int off = 1; off < 64; off <<= 1) {
            unsigned o = __shfl_up(s, off);
            if (ln >= off) s += o;
        }
        if (ln == 63) wexc[wv] = s;       // wave totals
        __syncthreads();
        if (tid < 16) {
            unsigned ws = wexc[tid];
            unsigned tt = ws;
#pragma unroll
            for (int off = 1; off < 16; off <<= 1) {
                unsigned o = __shfl_up(tt, off);
                if (tid >= off) tt += o;
            }
            wexc[tid] = tt - ws;          // exclusive wave offset
            if (tid == 15) chunk_total = tt;
        }
        __syncthreads();
        if (i < N) row_start[i] = (int)(carry + wexc[wv] + s - v);  // exclusive
        __syncthreads();
        if (tid == 0) carry += chunk_total;
        __syncthreads();
    }
    if (tid == 0) row_start[N] = (int)carry;  // == E
}
__global__ void scatter_kernel(const int* __restrict__ src, const int* __restrict__ dst,
                               const int* __restrict__ row_start,
                               unsigned* __restrict__ wcnt,
                               int* __restrict__ es, int* __restrict__ ed, int E) {
    int e = blockIdx.x * 256 + threadIdx.x;
    if (e >= E) return;
    int d = dst[e];
    int pos = row_start[d] + (int)atomicAdd(&wcnt[d], 1u);
    es[pos] = src[e];
    ed[pos] = d;
}

// ---- edges (layers 1,2): LDS-staged AF + MFMA + dst-owner seg-max -----------
// r10 structure with chunk 64->32 and single af buffer: block LDS 46.6->29.4 KB
// -> 5 blocks/CU (20 waves) instead of 3 (12). Per-edge instruction counts
// unchanged; more resident blocks overlap the barrier-coupled gather latency.
__global__ __launch_bounds__(256, 3)
void edge_seg_gemm_kernel(const unsigned short* __restrict__ RQb,
                          const int* __restrict__ es,
                          const int* __restrict__ ed,
                          const int* __restrict__ row_start,   // N+1
                          const unsigned short* __restrict__ W2T,  // [256][256]
                          const float* __restrict__ b2,
                          unsigned short* __restrict__ hcat,
                          int N, int E) {
    __shared__ unsigned short af[32][264];       // 16.9 KB, padded
    __shared__ unsigned short rdst[DPB][256];    // block's dst R-halves, 4 KB
    __shared__ unsigned lseg[DPB * 256];         // 8 KB
    __shared__ int ss[32], sdl[32];
    const int d0 = blockIdx.x * DPB;
    const int tid = threadIdx.x;
    const int wv = tid >> 6, lane = tid & 63;
    const int q = lane >> 4, nl = lane & 15;

    for (int i = tid; i < DPB * 256; i += 256) lseg[i] = ENC_NEG_INF;

    // load 8 dst rows (R half: RQb[d][0..255]) into LDS, b128 per thread
    {
        int rrow = tid >> 5;            // 0..7
        int kc = (tid & 31) * 8;        // 0..248
        int d = d0 + rrow;
        int dc = (d < N) ? d : (N - 1);
        *(bf16x8*)&rdst[rrow][kc] = *(const bf16x8*)(RQb + (size_t)dc * 512 + kc);
    }

    const int eBeg = row_start[d0];
    const int eEnd = row_start[min(d0 + DPB, N)];

    for (int c0 = eBeg; c0 < eEnd; c0 += 32) {
        __syncthreads();   // prior chunk fully consumed af/ss/sdl (also rdst ready)
        if (tid < 32) {
            int e = c0 + tid;
            ss[tid]  = (e < eEnd) ? es[e] : 0;
            sdl[tid] = (e < eEnd) ? (ed[e] - d0) : -1;
        }
        __syncthreads();

        // stage AF: 32 edges x 256 k; thread = (edge tid>>3, k-chunk (tid&7)*32)
        {
            const int el = tid >> 3;
            const int kc = (tid & 7) * 32;
            int dl = sdl[el];
            int dla = (dl >= 0) ? dl : 0;
            int srow = ss[el];
            const unsigned short* ps = RQb + (size_t)srow * 512 + 256 + kc;
#pragma unroll
            for (int j = 0; j < 4; ++j) {
                bf16x8 dv = *(const bf16x8*)&rdst[dla][kc + j * 8];
                bf16x8 sv = *(const bf16x8*)(ps + j * 8);
                float f[8];
#pragma unroll
                for (int u = 0; u < 8; ++u)
                    f[u] = fmaxf(bf2f((unsigned short)dv[u]) + bf2f((unsigned short)sv[u]), 0.f);
                uint4 o;
                o.x = pack_bf2(f[0], f[1]);
                o.y = pack_bf2(f[2], f[3]);
                o.z = pack_bf2(f[4], f[5]);
                o.w = pack_bf2(f[6], f[7]);
                *(uint4*)&af[el][kc + j * 8] = o;
            }
        }
        __syncthreads();

        // GEMM + segmented-max, one 16-edge subtile at a time (acc[4] only)
#pragma unroll
        for (int sub = 0; sub < 2; ++sub) {
            f32x4 acc[4];
#pragma unroll
            for (int t = 0; t < 4; ++t) acc[t] = (f32x4){0.f, 0.f, 0.f, 0.f};
#pragma unroll
            for (int ks = 0; ks < 8; ++ks) {
                const bf16x8 av = *(const bf16x8*)&af[sub * 16 + nl][ks * 32 + q * 8];
#pragma unroll
                for (int t = 0; t < 4; ++t) {
                    const bf16x8 bv = *(const bf16x8*)(W2T +
                        (size_t)(wv * 64 + t * 16 + nl) * 256 + ks * 32 + q * 8);
                    acc[t] = __builtin_amdgcn_mfma_f32_16x16x32_bf16(av, bv, acc[t], 0, 0, 0);
                }
            }
            // epilogue: lane holds rows m = sub*16 + q*4 + i, col = wv*64+t*16+nl
            const int m0 = sub * 16 + q * 4;
            int dls[4];
#pragma unroll
            for (int i = 0; i < 4; ++i) dls[i] = sdl[m0 + i];
#pragma unroll
            for (int t = 0; t < 4; ++t) {
                const int col = wv * 64 + t * 16 + nl;
                float cur = -INFINITY;
                int cd = dls[0];
#pragma unroll
                for (int i = 0; i < 4; ++i) {
                    int dl = dls[i];
                    if (dl != cd) {
                        if (cd >= 0) atomicMax(&lseg[cd * 256 + col], enc_f(cur));
                        cur = -INFINITY; cd = dl;
                    }
                    cur = fmaxf(cur, acc[t][i]);
                }
                if (cd >= 0) atomicMax(&lseg[cd * 256 + col], enc_f(cur));
            }
        }
    }
    __syncthreads();

    // write relu(max + b2) (0 for empty segments) straight into hcat (bf16)
    for (int i = tid; i < DPB * 256; i += 256) {
        int dl = i >> 8, col = i & 255;
        int d = d0 + dl;
        if (d >= N) continue;
        float f = dec_f(lseg[i]);
        float v = isfinite(f) ? fmaxf(f + b2[col], 0.f) : 0.f;
        hcat[(size_t)d * HC + col] = f2bf(v);
    }
}

// ---- layer 3 edges via MFMA: one wave per 16 sorted edges -------------------
__global__ __launch_bounds__(256)
void edge3_mfma_kernel(const unsigned short* __restrict__ RQb,
                       const int* __restrict__ es,
                       const int* __restrict__ ed,
                       const unsigned short* __restrict__ W2T3,  // [16][256]
                       const float* __restrict__ b2,             // 3
                       unsigned* __restrict__ seg3,
                       int E) {
    const int wave = blockIdx.x * 4 + (threadIdx.x >> 6);
    const int lane = threadIdx.x & 63;
    const int q = lane >> 4, nl = lane & 15;
    const int e0 = wave * 16;
    if (e0 >= E) return;

    // hoist all 8 B fragments (col nl, k = ks*32 + q*8 ..+7)
    bf16x8 bv[8];
#pragma unroll
    for (int ks = 0; ks < 8; ++ks)
        bv[ks] = *(const bf16x8*)(W2T3 + (size_t)nl * 256 + ks * 32 + q * 8);

    // this lane's A row: edge e0 + nl
    int eA = e0 + nl;
    int eAc = (eA < E) ? eA : (E - 1);
    const int dA = ed[eAc], sA = es[eAc];
    const unsigned short* pd = RQb + (size_t)dA * 512 + q * 8;
    const unsigned short* ps = RQb + (size_t)sA * 512 + 256 + q * 8;

    f32x4 acc = (f32x4){0.f, 0.f, 0.f, 0.f};
#pragma unroll
    for (int ks = 0; ks < 8; ++ks) {
        bf16x8 dv = *(const bf16x8*)(pd + ks * 32);
        bf16x8 sv = *(const bf16x8*)(ps + ks * 32);
        float f[8];
#pragma unroll
        for (int u = 0; u < 8; ++u)
            f[u] = fmaxf(bf2f((unsigned short)dv[u]) + bf2f((unsigned short)sv[u]), 0.f);
        uint4 o;
        o.x = pack_bf2(f[0], f[1]);
        o.y = pack_bf2(f[2], f[3]);
        o.z = pack_bf2(f[4], f[5]);
        o.w = pack_bf2(f[6], f[7]);
        bf16x8 av = *(bf16x8*)&o;
        acc = __builtin_amdgcn_mfma_f32_16x16x32_bf16(av, bv[ks], acc, 0, 0, 0);
    }

    // epilogue: col = nl (only nl<3), rows = q*4+i -> edges e0+q*4+i
    if (nl < 3) {
        float bb = b2[nl];
        float cur = -INFINITY;
        int cd = -2;
#pragma unroll
        for (int i = 0; i < 4; ++i) {
            int e = e0 + q * 4 + i;
            int d = (e < E) ? ed[e] : -1;
            if (d != cd) {
                if (cd >= 0) atomicMax(&seg3[(size_t)cd * 3 + nl], enc_f(cur + bb));
                cur = -INFINITY; cd = d;
            }
            if (d >= 0) cur = fmaxf(cur, acc[i]);
        }
        if (cd >= 0) atomicMax(&seg3[(size_t)cd * 3 + nl], enc_f(cur + bb));
    }
}

// ---------------- misc ------------------------------------------------------
__global__ void finalize3_kernel(const unsigned* __restrict__ seg3,
                                 const float* __restrict__ invstd,
                                 float* __restrict__ out, int N) {
    int idx = blockIdx.x * 256 + threadIdx.x;
    if (idx >= N * 3) return;
    int n = idx / 3;
    float f = dec_f(seg3[idx]);
    if (!isfinite(f)) f = 0.f;
    out[idx] = f * invstd[n];
}

extern "C" void kernel_launch(void* const* d_in, const int* in_sizes, int n_in,
                              void* d_out, int out_size, void* d_ws, size_t ws_size,
                              hipStream_t stream) {
    const float* x     = (const float*)d_in[0];
    const int*   ei    = (const int*)d_in[1];
    const float* t     = (const float*)d_in[2];
    const float* emb   = (const float*)d_in[3];
    const float* enc_W = (const float*)d_in[4];
    const float* enc_b = (const float*)d_in[5];
    const float* fw    = (const float*)d_in[6];
    const float* te_W  = (const float*)d_in[7];
    const float* te_b  = (const float*)d_in[8];
    const float* W1[3] = {(const float*)d_in[9],  (const float*)d_in[13], (const float*)d_in[17]};
    const float* b1[3] = {(const float*)d_in[10], (const float*)d_in[14], (const float*)d_in[18]};
    const float* W2[3] = {(const float*)d_in[11], (const float*)d_in[15], (const float*)d_in[19]};
    const float* b2[3] = {(const float*)d_in[12], (const float*)d_in[16], (const float*)d_in[20]};

    const int N = in_sizes[2];      // t is (N,1)
    const int E = in_sizes[1] / 2;  // edge_index is (2,E)
    const int* src = ei;
    const int* dst = ei + E;

    char* ws = (char*)d_ws;
    unsigned short* hcat  = (unsigned short*)ws; ws += (size_t)N * HC * 2;          // bf16
    unsigned short* RQb   = (unsigned short*)ws; ws += (size_t)N * 512 * 2;         // bf16
    unsigned short* WcatT = (unsigned short*)ws; ws += (size_t)3 * 512 * 768 * 2;   // bf16 x3
    unsigned short* W2T   = (unsigned short*)ws; ws += (size_t)2 * 256 * 256 * 2;   // bf16 x2
    unsigned short* W2T3  = (unsigned short*)ws; ws += (size_t)16 * 256 * 2;        // bf16
    unsigned* seg3        = (unsigned*)ws;       ws += (size_t)N * 3 * 4;
    float*    invstd      = (float*)ws;          ws += (size_t)N * 4;
    int*      es          = (int*)ws;            ws += (size_t)E * 4;
    int*      ed          = (int*)ws;            ws += (size_t)E * 4;
    unsigned* cnt         = (unsigned*)ws;       ws += (size_t)N * 4;   // cnt+wcnt adjacent
    unsigned* wcnt        = (unsigned*)ws;       ws += (size_t)N * 4;
    int*      row_start   = (int*)ws;            ws += (size_t)(N + 1) * 4;

    // ---- init (cnt/wcnt zero + seg3 neg-inf) + counting sort ----
    init_kernel<<<(5 * N + 255) / 256, 256, 0, stream>>>(cnt, seg3, N);
    hist_kernel<<<(E + 255) / 256, 256, 0, stream>>>(dst, cnt, E);
    scan_kernel<<<1, 1024, 0, stream>>>(cnt, row_start, N);
    scatter_kernel<<<(E + 255) / 256, 256, 0, stream>>>(src, dst, row_start, wcnt, es, ed, E);

    // fused precompute + weight prep
    const int nPre = (N + 7) / 8;
    pre_and_prep_kernel<<<nPre + 336, 256, 0, stream>>>(
        x, t, emb, enc_W, enc_b, fw, te_W, te_b, hcat, invstd,
        W1[0], W1[1], W1[2], W2[0], W2[1], W2[2], WcatT, W2T, W2T3, N, nPre);

    for (int l = 0; l < 3; ++l) {
        dim3 gn((N + 63) / 64, 4);
        node_gemm_mfma_kernel<<<gn, 256, 0, stream>>>(
            hcat, WcatT + (size_t)l * 512 * 768, b1[l], RQb, N);
        if (l < 2) {
            edge_seg_gemm_kernel<<<(N + DPB - 1) / DPB, 256, 0, stream>>>(
                RQb, es, ed, row_start, W2T + (size_t)l * 256 * 256, b2[l], hcat, N, E);
        } else {
            int chunks = (E + 15) / 16;
            edge3_mfma_kernel<<<(chunks + 3) / 4, 256, 0, stream>>>(
                RQb, es, ed, W2T3, b2[l], seg3, E);
            finalize3_kernel<<<(N * 3 + 255) / 256, 256, 0, stream>>>(seg3, invstd, (float*)d_out, N);
        }
    }
}